// Round 10
// baseline (22.712 us; speedup 1.0000x reference)
//
#include <hip/hip_runtime.h>

#define NB 8
#define NN 512
#define DD 64

typedef short bf16x8 __attribute__((ext_vector_type(8)));
typedef float f32x4 __attribute__((ext_vector_type(4)));

__device__ __forceinline__ unsigned short f2bf(float f) {
    unsigned int x = __builtin_bit_cast(unsigned int, f);
    x += 0x7FFFu + ((x >> 16) & 1u);      // round-to-nearest-even (finite inputs)
    return (unsigned short)(x >> 16);
}

__device__ __forceinline__ void gload_lds16(const void* g, void* lds) {
    __builtin_amdgcn_global_load_lds(
        (const __attribute__((address_space(1))) unsigned int*)g,
        (__attribute__((address_space(3))) unsigned int*)lds, 16, 0, 0);
}

// one-hot A-fragment from 16 packed 2-bit fields; rep = cls * 0x55555555
__device__ __forceinline__ bf16x8 onehot_packed(unsigned int bits, unsigned int rep) {
    unsigned int x = bits ^ rep;           // field == 0 where class matches
    unsigned int y = x | (x >> 1);
    unsigned int m = ~y & 0x55555555u;     // bit 2i = match_i
    union { unsigned int u[4]; bf16x8 v; } r;
    #pragma unroll
    for (int j = 0; j < 4; ++j) {
        unsigned int f = m >> (4 * j);
        r.u[j] = ((f & 1u) ? 0x3F80u : 0u) | ((f & 4u) ? 0x3F800000u : 0u);
    }
    return r.v;
}

// ---- prep (tiny): h -> HTbf2 slab image (64 blocks) + W convert (128 blocks) ----
// HTbf2 slab layout (u16): [b][slab=(c*4+kc)*4+n][kb][r][j]
//   = bf16(h[b][ w = c*128+kc*32+kb*8+j ][ e = n*16+r ])  (verified R9)
__global__ __launch_bounds__(256) void prep_kernel(
    const float* __restrict__ h,
    const float* __restrict__ Min, const float* __restrict__ Mout,
    unsigned short* __restrict__ HTbf2, unsigned short* __restrict__ Wbf)
{
    const int blk = blockIdx.x, t = threadIdx.x;
    if (blk < 64) {                        // h -> HTbf2 slab image, tiled
        __shared__ float tf[64][65];
        const int b = blk >> 3, w0 = (blk & 7) * 64;
        #pragma unroll
        for (int i = 0; i < 16; ++i) {
            int idx = i * 256 + t, w = idx >> 6, e = idx & 63;
            tf[w][e] = h[((size_t)b * NN + w0 + w) * DD + e];   // coalesced
        }
        __syncthreads();
        unsigned int* HT32 = (unsigned int*)HTbf2;
        const int n = t >> 6, r = (t >> 2) & 15, p = t & 3;
        #pragma unroll
        for (int i = 0; i < 8; ++i) {
            int woct = (w0 >> 3) + i;                  // global oct in [0,64)
            int kb = woct & 3, kc = (woct >> 2) & 3, cch = woct >> 4;
            int slab = (cch * 4 + kc) * 4 + n;
            unsigned int lo = f2bf(tf[8 * i + 2 * p][n * 16 + r]);
            unsigned int hi = f2bf(tf[8 * i + 2 * p + 1][n * 16 + r]);
            HT32[(size_t)b * 16384 + slab * 256 + kb * 64 + r * 4 + p] =
                lo | (hi << 16);
        }
    } else {                               // Wbf[dir][d][c*64+e] = bf16(M[c][d][e])
        int idx = (blk - 64) * 256 + t;
        int dir = idx >> 14, d = (idx >> 8) & 63, k = idx & 255;
        int c = k >> 6, e = k & 63;
        const float* M = dir ? Mout : Min;
        Wbf[idx] = f2bf(M[(c * DD + d) * DD + e]);
    }
}

// ---------------- main: self-packing + slab MFMA, single barrier ----------------
// block = (b = blk&7, XCD-pinned batch; v0 = (blk>>3)*8). 4 waves = (dir, rt).
__global__ __launch_bounds__(256) void msg_mfma_kernel(
    const int* __restrict__ adj,
    const unsigned short* __restrict__ HTbf2, const unsigned short* __restrict__ Wbf,
    const float* __restrict__ bias, float* __restrict__ out)
{
    __shared__ __align__(16) unsigned short HTX[64][512]; // 64 slabs x 1 KB
    __shared__ unsigned short S2[2][8][256];              // 8 KB (verified R6 path)
    __shared__ __align__(16) unsigned int pR[8][32];      // 1 KB row-pack
    __shared__ __align__(16) unsigned int pC[8][32];      // 1 KB col-pack

    const int t = threadIdx.x;
    const int lane = t & 63, wv = t >> 6;
    const int dir = wv >> 1, rt = wv & 1;
    const int b  = blockIdx.x & 7;            // XCD-pinned batch
    const int v0 = (blockIdx.x >> 3) * 8;
    const int r = lane & 15, kb = lane >> 4;

    const int* adjb = adj + (size_t)b * NN * NN;
    const unsigned short* HTg = HTbf2 + (size_t)b * 32768;

    // ---- stage all 64 slabs (16/wave), linear src AND dest (verified R9) ----
    #pragma unroll
    for (int q = 0; q < 16; ++q) {
        int s = wv * 16 + q;
        gload_lds16(HTg + (size_t)s * 512 + lane * 8, &HTX[s][0]);
    }

    // ---- A1: row-pack pR[v][pk], coalesced int4 reads (verified R7) ----
    {
        int v = t >> 5, pk = t & 31;
        const int* src = adjb + (size_t)(v0 + v) * NN + pk * 16;
        int4 a0 = *(const int4*)(src + 0),  a1 = *(const int4*)(src + 4);
        int4 a2 = *(const int4*)(src + 8),  a3 = *(const int4*)(src + 12);
        unsigned int u =
            ((unsigned int)a0.x & 3u)        | (((unsigned int)a0.y & 3u) << 2)  |
            (((unsigned int)a0.z & 3u) << 4) | (((unsigned int)a0.w & 3u) << 6)  |
            (((unsigned int)a1.x & 3u) << 8) | (((unsigned int)a1.y & 3u) << 10) |
            (((unsigned int)a1.z & 3u) << 12)| (((unsigned int)a1.w & 3u) << 14) |
            (((unsigned int)a2.x & 3u) << 16)| (((unsigned int)a2.y & 3u) << 18) |
            (((unsigned int)a2.z & 3u) << 20)| (((unsigned int)a2.w & 3u) << 22) |
            (((unsigned int)a3.x & 3u) << 24)| (((unsigned int)a3.y & 3u) << 26) |
            (((unsigned int)a3.z & 3u) << 28)| (((unsigned int)a3.w & 3u) << 30);
        pR[v][pk] = u;
    }

    // ---- A2: col-pack pC via 16-lane shfl_xor OR-butterfly (verified R7) ----
    // adj[b] is XCD-L2-resident (row-readers of the same batch share the lines).
    #pragma unroll
    for (int it = 0; it < 2; ++it) {
        int w = it * 256 + t;
        const int* src = adjb + (size_t)w * NN + v0;   // 32B, 16B-aligned
        int4 a0 = *(const int4*)src, a1 = *(const int4*)(src + 4);
        int sh = 2 * (w & 15);
        #pragma unroll
        for (int v = 0; v < 8; ++v) {
            int av = (v==0)?a0.x:(v==1)?a0.y:(v==2)?a0.z:(v==3)?a0.w:
                     (v==4)?a1.x:(v==5)?a1.y:(v==6)?a1.z:a1.w;
            unsigned int u = ((unsigned int)av & 3u) << sh;
            u |= __shfl_xor(u, 1);  u |= __shfl_xor(u, 2);
            u |= __shfl_xor(u, 4);  u |= __shfl_xor(u, 8);
            if ((t & 15) == v) pC[v][w >> 4] = u;
        }
    }

    __syncthreads();   // ONE barrier: drains 64 slab loads + orders pR/pC

    // ---- A-operand bits from LDS packs ----
    const int vloc = rt * 4 + (r >> 2);
    const unsigned int rep = (unsigned int)(r & 3) * 0x55555555u;
    const unsigned short* prow =
        (const unsigned short*)(dir ? &pC[vloc][0] : &pR[vloc][0]);
    unsigned int bits0  = prow[kb];        unsigned int bits1  = prow[4 + kb];
    unsigned int bits2  = prow[8 + kb];    unsigned int bits3  = prow[12 + kb];
    unsigned int bits4  = prow[16 + kb];   unsigned int bits5  = prow[20 + kb];
    unsigned int bits6  = prow[24 + kb];   unsigned int bits7  = prow[28 + kb];
    unsigned int bits8  = prow[32 + kb];   unsigned int bits9  = prow[36 + kb];
    unsigned int bits10 = prow[40 + kb];   unsigned int bits11 = prow[44 + kb];
    unsigned int bits12 = prow[48 + kb];   unsigned int bits13 = prow[52 + kb];
    unsigned int bits14 = prow[56 + kb];   unsigned int bits15 = prow[60 + kb];

    // ---- phase 1: S[(v,c),e] = sum_w onehot * h — conflict-free slab reads ----
    f32x4 acc[4] = {f32x4{0,0,0,0}, f32x4{0,0,0,0}, f32x4{0,0,0,0}, f32x4{0,0,0,0}};
    #pragma unroll
    for (int c = 0; c < 4; ++c) {
        #pragma unroll
        for (int kc = 0; kc < 4; ++kc) {
            unsigned int bits;
            switch (c * 4 + kc) {         // compile-time after unroll
                case 0:  bits = bits0;  break;  case 1:  bits = bits1;  break;
                case 2:  bits = bits2;  break;  case 3:  bits = bits3;  break;
                case 4:  bits = bits4;  break;  case 5:  bits = bits5;  break;
                case 6:  bits = bits6;  break;  case 7:  bits = bits7;  break;
                case 8:  bits = bits8;  break;  case 9:  bits = bits9;  break;
                case 10: bits = bits10; break;  case 11: bits = bits11; break;
                case 12: bits = bits12; break;  case 13: bits = bits13; break;
                case 14: bits = bits14; break;  default: bits = bits15; break;
            }
            bf16x8 afrag = onehot_packed(bits, rep);
            #pragma unroll
            for (int n = 0; n < 4; ++n) {
                bf16x8 bfrag = *(const bf16x8*)&HTX[(c * 4 + kc) * 4 + n][lane * 8];
                acc[n] = __builtin_amdgcn_mfma_f32_16x16x32_bf16(afrag, bfrag, acc[n], 0, 0, 0);
            }
        }
    }

    // ---- S -> LDS (bf16, XOR-swizzled rows; verified R6 path) ----
    #pragma unroll
    for (int ct = 0; ct < 4; ++ct) {
        #pragma unroll
        for (int rg = 0; rg < 4; ++rg) {
            int row_g = rt * 16 + kb * 4 + rg;        // 0..31 = (v,c)
            int vv = row_g >> 2, cc2 = row_g & 3;
            int e = ct * 16 + r;
            int rb = (cc2 * 128 + e * 2) ^ ((vv & 7) << 4);
            *(unsigned short*)((char*)&S2[dir][vv][0] + rb) = f2bf(acc[ct][rg]);
        }
    }
    __syncthreads();

    // ---- phase 2: out[v, dir*64+d] = sum_{c,e} S[v,(c,e)] * W[(c,e),d] + bias ----
    f32x4 acc2[2] = {f32x4{0,0,0,0}, f32x4{0,0,0,0}};
    #pragma unroll
    for (int kc = 0; kc < 8; ++kc) {
        int vv = r & 7;                               // A rows 8..15 duplicate 0..7
        int kbase = kc * 32 + kb * 8;
        int rb = (kbase * 2) ^ (vv << 4);
        bf16x8 a2 = *(const bf16x8*)((const char*)&S2[dir][vv][0] + rb);
        #pragma unroll
        for (int j = 0; j < 2; ++j) {
            int d = (rt * 2 + j) * 16 + r;
            bf16x8 b2 = *(const bf16x8*)&Wbf[(dir * DD + d) * 256 + kbase];
            acc2[j] = __builtin_amdgcn_mfma_f32_16x16x32_bf16(a2, b2, acc2[j], 0, 0, 0);
        }
    }
    #pragma unroll
    for (int j = 0; j < 2; ++j) {
        int d = (rt * 2 + j) * 16 + r;
        float bs = bias[dir * DD + d];
        #pragma unroll
        for (int rg = 0; rg < 4; ++rg) {
            int row = kb * 4 + rg;                    // duplicated rows >=8 skipped
            if (row < 8)
                out[((size_t)(b * NN + v0 + row)) * (2 * DD) + dir * DD + d] = acc2[j][rg] + bs;
        }
    }
}

// ---------------- fallback (R1 kernel, used only if ws too small) ----------------
__global__ __launch_bounds__(256) void msg_kernel(
    const float* __restrict__ h, const int* __restrict__ adj,
    const float* __restrict__ Min, const float* __restrict__ Mout,
    const float* __restrict__ bias, float* __restrict__ out)
{
    __shared__ __align__(16) float S[4][2][4][DD];
    const int lane = threadIdx.x & 63, wslot = threadIdx.x >> 6;
    const int wid = blockIdx.x * 4 + wslot;
    const int b = wid >> 9, v = wid & (NN - 1);
    const float* hb = h + (size_t)b * NN * DD;
    const int* adjb = adj + (size_t)b * NN * NN;
    float tot = 0.f, ain1 = 0.f, ain2 = 0.f, ain3 = 0.f, aout1 = 0.f, aout2 = 0.f, aout3 = 0.f;
    for (int w0 = 0; w0 < NN; w0 += 64) {
        int cin_chunk = adjb[v * NN + (w0 + lane)];
        int cout_chunk = adjb[(w0 + lane) * NN + v];
        #pragma unroll
        for (int k = 0; k < 64; ++k) {
            float hw = hb[(w0 + k) * DD + lane];
            int cin = __builtin_amdgcn_readlane(cin_chunk, k);
            int cout = __builtin_amdgcn_readlane(cout_chunk, k);
            tot += hw;
            ain1 = fmaf((cin == 1) ? 1.f : 0.f, hw, ain1);
            ain2 = fmaf((cin == 2) ? 1.f : 0.f, hw, ain2);
            ain3 = fmaf((cin == 3) ? 1.f : 0.f, hw, ain3);
            aout1 = fmaf((cout == 1) ? 1.f : 0.f, hw, aout1);
            aout2 = fmaf((cout == 2) ? 1.f : 0.f, hw, aout2);
            aout3 = fmaf((cout == 3) ? 1.f : 0.f, hw, aout3);
        }
    }
    S[wslot][0][0][lane] = tot - ain1 - ain2 - ain3;
    S[wslot][0][1][lane] = ain1; S[wslot][0][2][lane] = ain2; S[wslot][0][3][lane] = ain3;
    S[wslot][1][0][lane] = tot - aout1 - aout2 - aout3;
    S[wslot][1][1][lane] = aout1; S[wslot][1][2][lane] = aout2; S[wslot][1][3][lane] = aout3;
    __syncthreads();
    float o_in = 0.f, o_out = 0.f;
    #pragma unroll
    for (int c = 0; c < 4; ++c)
        for (int e0 = 0; e0 < DD; e0 += 4) {
            float4 mi = *reinterpret_cast<const float4*>(&Min[(c * DD + lane) * DD + e0]);
            float4 mo = *reinterpret_cast<const float4*>(&Mout[(c * DD + lane) * DD + e0]);
            float4 si = *reinterpret_cast<const float4*>(&S[wslot][0][c][e0]);
            float4 so = *reinterpret_cast<const float4*>(&S[wslot][1][c][e0]);
            o_in = fmaf(mi.x, si.x, fmaf(mi.y, si.y, fmaf(mi.z, si.z, fmaf(mi.w, si.w, o_in))));
            o_out = fmaf(mo.x, so.x, fmaf(mo.y, so.y, fmaf(mo.z, so.z, fmaf(mo.w, so.w, o_out))));
        }
    float* ov = out + (size_t)(b * NN + v) * (2 * DD);
    ov[lane] = o_in + bias[lane];
    ov[DD + lane] = o_out + bias[DD + lane];
}

extern "C" void kernel_launch(void* const* d_in, const int* in_sizes, int n_in,
                              void* d_out, int out_size, void* d_ws, size_t ws_size,
                              hipStream_t stream) {
    const float* node_state = (const float*)d_in[0];
    const int*   adj_mat    = (const int*)  d_in[1];
    const float* matrix_in  = (const float*)d_in[2];
    const float* matrix_out = (const float*)d_in[3];
    const float* bias       = (const float*)d_in[4];
    float* out = (float*)d_out;

    const size_t HT_OFF = 0;                                   // 512 KB
    const size_t W_OFF  = (size_t)NB * 32768 * 2;              // +64 KB
    const size_t NEED   = W_OFF + (size_t)2 * DD * 256 * 2;

    if (ws_size < NEED) {   // scratch too small: proven-correct R1 path
        msg_kernel<<<NB * NN / 4, 256, 0, stream>>>(node_state, adj_mat, matrix_in,
                                                    matrix_out, bias, out);
        return;
    }
    unsigned short* HTbf2 = (unsigned short*)((char*)d_ws + HT_OFF);
    unsigned short* Wbf   = (unsigned short*)((char*)d_ws + W_OFF);

    prep_kernel<<<192, 256, 0, stream>>>(node_state, matrix_in, matrix_out,
                                         HTbf2, Wbf);
    msg_mfma_kernel<<<NB * NN / 8, 256, 0, stream>>>(adj_mat, HTbf2, Wbf, bias, out);
}

// Round 11
// 21.724 us; speedup vs baseline: 1.0454x; 1.0454x over previous
//
#include <hip/hip_runtime.h>

#define NB 8
#define NN 512
#define DD 64

typedef short bf16x8 __attribute__((ext_vector_type(8)));
typedef float f32x4 __attribute__((ext_vector_type(4)));

__device__ __forceinline__ unsigned short f2bf(float f) {
    unsigned int x = __builtin_bit_cast(unsigned int, f);
    x += 0x7FFFu + ((x >> 16) & 1u);      // round-to-nearest-even (finite inputs)
    return (unsigned short)(x >> 16);
}

// one-hot A-fragment from 16 packed 2-bit fields; rep = cls * 0x55555555
__device__ __forceinline__ bf16x8 onehot_packed(unsigned int bits, unsigned int rep) {
    unsigned int x = bits ^ rep;           // field == 0 where class matches
    unsigned int y = x | (x >> 1);
    unsigned int m = ~y & 0x55555555u;     // bit 2i = match_i
    union { unsigned int u[4]; bf16x8 v; } r;
    #pragma unroll
    for (int j = 0; j < 4; ++j) {
        unsigned int f = m >> (4 * j);
        r.u[j] = ((f & 1u) ? 0x3F80u : 0u) | ((f & 4u) ? 0x3F800000u : 0u);
    }
    return r.v;
}

// ------------- ONE dispatch: self-sufficient blocks, zero shared prep -------------
// block = (b = blk&7 -> XCD-pinned batch, v0 = (blk>>3)*8). 4 waves = (dir, rt).
// Slab layout (verified R9): HTX[s=(c*4+kc)*4+n][lane*8+j] = bf16(h[b][c*128+kc*32+
// (lane>>4)*8+j][n*16+(lane&15)]) — each MFMA B-fragment is 64 lanes x 16B linear.
__global__ __launch_bounds__(256) void msg_one_kernel(
    const float* __restrict__ h, const int* __restrict__ adj,
    const float* __restrict__ Min, const float* __restrict__ Mout,
    const float* __restrict__ bias, float* __restrict__ out)
{
    __shared__ __align__(16) unsigned short HTX[64][512]; // 64 slabs x 1 KB
    __shared__ unsigned short S2[2][8][256];              // 8 KB (verified R6 path)
    __shared__ __align__(16) unsigned int pR[8][32];      // 1 KB row-pack
    __shared__ __align__(16) unsigned int pC[8][32];      // 1 KB col-pack

    const int t = threadIdx.x;
    const int lane = t & 63, wv = t >> 6;
    const int dir = wv >> 1, rt = wv & 1;
    const int b  = blockIdx.x & 7;            // XCD-pinned batch
    const int v0 = (blockIdx.x >> 3) * 8;
    const int r = lane & 15, kb = lane >> 4;

    const int*   adjb = adj + (size_t)b * NN * NN;
    const float* hb   = h   + (size_t)b * NN * DD;

    // ---- A0: h -> HTX slab image, DIRECT strided global reads (no LDS tile) ----
    // Per (wave, q): slab s = wv*16+q. Lane reads 8 f32 at stride 256B; within a
    // 16-lane group (fixed kb) the 16 r's are 64B-contiguous -> 4 lines/instr.
    // h[b] (128 KB) is XCD-L2-resident: all 64 blocks of batch b share it.
    #pragma unroll
    for (int q = 0; q < 16; ++q) {
        int s = wv * 16 + q;
        int c = s >> 4, kc = (s >> 2) & 3, n = s & 3;
        const float* src = hb + (size_t)(c * 128 + kc * 32 + kb * 8) * DD + n * 16 + r;
        unsigned int u0, u1, u2, u3;
        u0 = f2bf(src[0 * DD]) | ((unsigned int)f2bf(src[1 * DD]) << 16);
        u1 = f2bf(src[2 * DD]) | ((unsigned int)f2bf(src[3 * DD]) << 16);
        u2 = f2bf(src[4 * DD]) | ((unsigned int)f2bf(src[5 * DD]) << 16);
        u3 = f2bf(src[6 * DD]) | ((unsigned int)f2bf(src[7 * DD]) << 16);
        uint4 pkt; pkt.x = u0; pkt.y = u1; pkt.z = u2; pkt.w = u3;
        *(uint4*)&HTX[s][lane * 8] = pkt;     // ds_write_b128, linear, conflict-free
    }

    // ---- A1: row-pack pR[v][pk], coalesced int4 reads (verified R7/R10) ----
    {
        int v = t >> 5, pk = t & 31;
        const int* src = adjb + (size_t)(v0 + v) * NN + pk * 16;
        int4 a0 = *(const int4*)(src + 0),  a1 = *(const int4*)(src + 4);
        int4 a2 = *(const int4*)(src + 8),  a3 = *(const int4*)(src + 12);
        unsigned int u =
            ((unsigned int)a0.x & 3u)        | (((unsigned int)a0.y & 3u) << 2)  |
            (((unsigned int)a0.z & 3u) << 4) | (((unsigned int)a0.w & 3u) << 6)  |
            (((unsigned int)a1.x & 3u) << 8) | (((unsigned int)a1.y & 3u) << 10) |
            (((unsigned int)a1.z & 3u) << 12)| (((unsigned int)a1.w & 3u) << 14) |
            (((unsigned int)a2.x & 3u) << 16)| (((unsigned int)a2.y & 3u) << 18) |
            (((unsigned int)a2.z & 3u) << 20)| (((unsigned int)a2.w & 3u) << 22) |
            (((unsigned int)a3.x & 3u) << 24)| (((unsigned int)a3.y & 3u) << 26) |
            (((unsigned int)a3.z & 3u) << 28)| (((unsigned int)a3.w & 3u) << 30);
        pR[v][pk] = u;
    }

    // ---- A2: col-pack pC via 16-lane shfl_xor OR-butterfly (verified R7/R10) ----
    #pragma unroll
    for (int it = 0; it < 2; ++it) {
        int w = it * 256 + t;
        const int* src = adjb + (size_t)w * NN + v0;   // 32B, L2-hit (XCD-resident)
        int4 a0 = *(const int4*)src, a1 = *(const int4*)(src + 4);
        int sh = 2 * (w & 15);
        #pragma unroll
        for (int v = 0; v < 8; ++v) {
            int av = (v==0)?a0.x:(v==1)?a0.y:(v==2)?a0.z:(v==3)?a0.w:
                     (v==4)?a1.x:(v==5)?a1.y:(v==6)?a1.z:a1.w;
            unsigned int u = ((unsigned int)av & 3u) << sh;
            u |= __shfl_xor(u, 1);  u |= __shfl_xor(u, 2);
            u |= __shfl_xor(u, 4);  u |= __shfl_xor(u, 8);
            if ((t & 15) == v) pC[v][w >> 4] = u;
        }
    }

    __syncthreads();   // ONE barrier: HTX writes + pR/pC visible to all waves

    // ---- A-operand bits from LDS packs ----
    const int vloc = rt * 4 + (r >> 2);
    const unsigned int rep = (unsigned int)(r & 3) * 0x55555555u;
    const unsigned short* prow =
        (const unsigned short*)(dir ? &pC[vloc][0] : &pR[vloc][0]);
    unsigned int bits0  = prow[kb];        unsigned int bits1  = prow[4 + kb];
    unsigned int bits2  = prow[8 + kb];    unsigned int bits3  = prow[12 + kb];
    unsigned int bits4  = prow[16 + kb];   unsigned int bits5  = prow[20 + kb];
    unsigned int bits6  = prow[24 + kb];   unsigned int bits7  = prow[28 + kb];
    unsigned int bits8  = prow[32 + kb];   unsigned int bits9  = prow[36 + kb];
    unsigned int bits10 = prow[40 + kb];   unsigned int bits11 = prow[44 + kb];
    unsigned int bits12 = prow[48 + kb];   unsigned int bits13 = prow[52 + kb];
    unsigned int bits14 = prow[56 + kb];   unsigned int bits15 = prow[60 + kb];

    // ---- phase 1: S[(v,c),e] = sum_w onehot * h — conflict-free slab reads ----
    f32x4 acc[4] = {f32x4{0,0,0,0}, f32x4{0,0,0,0}, f32x4{0,0,0,0}, f32x4{0,0,0,0}};
    #pragma unroll
    for (int c = 0; c < 4; ++c) {
        #pragma unroll
        for (int kc = 0; kc < 4; ++kc) {
            unsigned int bits;
            switch (c * 4 + kc) {         // compile-time after unroll
                case 0:  bits = bits0;  break;  case 1:  bits = bits1;  break;
                case 2:  bits = bits2;  break;  case 3:  bits = bits3;  break;
                case 4:  bits = bits4;  break;  case 5:  bits = bits5;  break;
                case 6:  bits = bits6;  break;  case 7:  bits = bits7;  break;
                case 8:  bits = bits8;  break;  case 9:  bits = bits9;  break;
                case 10: bits = bits10; break;  case 11: bits = bits11; break;
                case 12: bits = bits12; break;  case 13: bits = bits13; break;
                case 14: bits = bits14; break;  default: bits = bits15; break;
            }
            bf16x8 afrag = onehot_packed(bits, rep);
            #pragma unroll
            for (int n = 0; n < 4; ++n) {
                bf16x8 bfrag = *(const bf16x8*)&HTX[(c * 4 + kc) * 4 + n][lane * 8];
                acc[n] = __builtin_amdgcn_mfma_f32_16x16x32_bf16(afrag, bfrag, acc[n], 0, 0, 0);
            }
        }
    }

    // ---- S -> LDS (bf16, XOR-swizzled rows; verified R6 path) ----
    #pragma unroll
    for (int ct = 0; ct < 4; ++ct) {
        #pragma unroll
        for (int rg = 0; rg < 4; ++rg) {
            int row_g = rt * 16 + kb * 4 + rg;        // 0..31 = (v,c)
            int vv = row_g >> 2, cc2 = row_g & 3;
            int e = ct * 16 + r;
            int rb = (cc2 * 128 + e * 2) ^ ((vv & 7) << 4);
            *(unsigned short*)((char*)&S2[dir][vv][0] + rb) = f2bf(acc[ct][rg]);
        }
    }
    __syncthreads();

    // ---- phase 2: W-fragments direct from global f32 (L2/L1-hot; verified R7) ----
    const float* Mrow = dir ? Mout : Min;
    f32x4 acc2[2] = {f32x4{0,0,0,0}, f32x4{0,0,0,0}};
    #pragma unroll
    for (int kc = 0; kc < 8; ++kc) {
        int vv = r & 7;                               // A rows 8..15 duplicate 0..7
        int kbase = kc * 32 + kb * 8;
        int rb = (kbase * 2) ^ (vv << 4);
        bf16x8 a2 = *(const bf16x8*)((const char*)&S2[dir][vv][0] + rb);
        #pragma unroll
        for (int j = 0; j < 2; ++j) {
            int d = (rt * 2 + j) * 16 + r;
            const float* wsrc = &Mrow[((size_t)(kbase >> 6) * DD + d) * DD + (kbase & 63)];
            float4 f0 = *(const float4*)wsrc;
            float4 f1 = *(const float4*)(wsrc + 4);
            union { unsigned int u[4]; bf16x8 v; } b2;
            b2.u[0] = f2bf(f0.x) | ((unsigned int)f2bf(f0.y) << 16);
            b2.u[1] = f2bf(f0.z) | ((unsigned int)f2bf(f0.w) << 16);
            b2.u[2] = f2bf(f1.x) | ((unsigned int)f2bf(f1.y) << 16);
            b2.u[3] = f2bf(f1.z) | ((unsigned int)f2bf(f1.w) << 16);
            acc2[j] = __builtin_amdgcn_mfma_f32_16x16x32_bf16(a2, b2.v, acc2[j], 0, 0, 0);
        }
    }
    #pragma unroll
    for (int j = 0; j < 2; ++j) {
        int d = (rt * 2 + j) * 16 + r;
        float bs = bias[dir * DD + d];
        #pragma unroll
        for (int rg = 0; rg < 4; ++rg) {
            int row = kb * 4 + rg;                    // duplicated rows >=8 skipped
            if (row < 8)
                out[((size_t)(b * NN + v0 + row)) * (2 * DD) + dir * DD + d] = acc2[j][rg] + bs;
        }
    }
}

extern "C" void kernel_launch(void* const* d_in, const int* in_sizes, int n_in,
                              void* d_out, int out_size, void* d_ws, size_t ws_size,
                              hipStream_t stream) {
    const float* node_state = (const float*)d_in[0];
    const int*   adj_mat    = (const int*)  d_in[1];
    const float* matrix_in  = (const float*)d_in[2];
    const float* matrix_out = (const float*)d_in[3];
    const float* bias       = (const float*)d_in[4];
    float* out = (float*)d_out;

    msg_one_kernel<<<NB * NN / 8, 256, 0, stream>>>(
        node_state, adj_mat, matrix_in, matrix_out, bias, out);
}

// Round 12
// 21.331 us; speedup vs baseline: 1.0647x; 1.0185x over previous
//
#include <hip/hip_runtime.h>

#define NB 8
#define NN 512
#define DD 64

typedef short bf16x8 __attribute__((ext_vector_type(8)));
typedef float f32x4 __attribute__((ext_vector_type(4)));

__device__ __forceinline__ unsigned short f2bf(float f) {
    unsigned int x = __builtin_bit_cast(unsigned int, f);
    x += 0x7FFFu + ((x >> 16) & 1u);      // round-to-nearest-even (finite inputs)
    return (unsigned short)(x >> 16);
}

// one-hot A-fragment from 16 packed 2-bit fields; rep = cls * 0x55555555
__device__ __forceinline__ bf16x8 onehot_packed(unsigned int bits, unsigned int rep) {
    unsigned int x = bits ^ rep;           // field == 0 where class matches
    unsigned int y = x | (x >> 1);
    unsigned int m = ~y & 0x55555555u;     // bit 2i = match_i
    union { unsigned int u[4]; bf16x8 v; } r;
    #pragma unroll
    for (int j = 0; j < 4; ++j) {
        unsigned int f = m >> (4 * j);
        r.u[j] = ((f & 1u) ? 0x3F80u : 0u) | ((f & 4u) ? 0x3F800000u : 0u);
    }
    return r.v;
}

// ---- prep: adj read ONCE -> packR+packC (verified R5); h -> slab; M -> Wbf ----
// HTbf2 slab layout (u16): [b][slab=(c*4+kc)*4+n][kb][r][j]
//   = bf16(h[b][ w = c*128+kc*32+kb*8+j ][ e = n*16+r ])  (verified R9)
__global__ __launch_bounds__(256) void prep_kernel(
    const float* __restrict__ h, const int* __restrict__ adj,
    const float* __restrict__ Min, const float* __restrict__ Mout,
    unsigned int* __restrict__ packR, unsigned int* __restrict__ packC,
    unsigned short* __restrict__ HTbf2, unsigned short* __restrict__ Wbf)
{
    const int blk = blockIdx.x, t = threadIdx.x;
    if (blk < 512) {                       // adj tile: emit row-pack AND col-pack
        __shared__ int tile[64][65];
        const int b = blk >> 6, ti = blk & 63;
        const int tr = (ti >> 3) * 64, tc = (ti & 7) * 64;
        const int* src = adj + (size_t)b * NN * NN;
        #pragma unroll
        for (int i = 0; i < 16; ++i) {
            int idx = i * 256 + t, rr = idx >> 6, cc = idx & 63;
            tile[rr][cc] = src[(size_t)(tr + rr) * NN + tc + cc];
        }
        __syncthreads();
        {
            int r = t >> 2, g = t & 3;
            unsigned int ur = 0, uc = 0;
            #pragma unroll
            for (int j = 0; j < 16; ++j) {
                ur |= ((unsigned int)tile[r][16 * g + j] & 3u) << (2 * j);
                uc |= ((unsigned int)tile[16 * g + j][r] & 3u) << (2 * j);
            }
            packR[((size_t)b * NN + tr + r) * 32 + (tc >> 4) + g] = ur;
            packC[((size_t)b * NN + tc + r) * 32 + (tr >> 4) + g] = uc;
        }
    } else if (blk < 576) {                // h -> HTbf2 slab image (verified R9)
        __shared__ float tf[64][65];
        const int bb = blk - 512, b = bb >> 3, w0 = (bb & 7) * 64;
        #pragma unroll
        for (int i = 0; i < 16; ++i) {
            int idx = i * 256 + t, w = idx >> 6, e = idx & 63;
            tf[w][e] = h[((size_t)b * NN + w0 + w) * DD + e];   // coalesced
        }
        __syncthreads();
        unsigned int* HT32 = (unsigned int*)HTbf2;
        const int n = t >> 6, r = (t >> 2) & 15, p = t & 3;
        #pragma unroll
        for (int i = 0; i < 8; ++i) {
            int woct = (w0 >> 3) + i;                  // global oct in [0,64)
            int kb = woct & 3, kc = (woct >> 2) & 3, cch = woct >> 4;
            int slab = (cch * 4 + kc) * 4 + n;
            unsigned int lo = f2bf(tf[8 * i + 2 * p][n * 16 + r]);
            unsigned int hi = f2bf(tf[8 * i + 2 * p + 1][n * 16 + r]);
            HT32[(size_t)b * 16384 + slab * 256 + kb * 64 + r * 4 + p] =
                lo | (hi << 16);
        }
    } else {                               // Wbf[dir][d][c*64+e] = bf16(M[c][d][e])
        int idx = (blk - 576) * 256 + t;
        int dir = idx >> 14, d = (idx >> 8) & 63, k = idx & 255;
        int c = k >> 6, e = k & 63;
        const float* M = dir ? Mout : Min;
        Wbf[idx] = f2bf(M[(c * DD + d) * DD + e]);
    }
}

// ---------- main: NO LDS H-tile. B-fragments direct from L2-hot slab image ----------
// block = (b = blk&7 -> XCD-pinned, v0 = (blk>>3)*8). 4 waves = (dir, rt).
// LDS = 8KB (S2 only) -> occupancy VGPR-bound (~4-5 blocks/CU vs previous 2).
__global__ __launch_bounds__(256) void msg_mfma_kernel(
    const unsigned int* __restrict__ packR, const unsigned int* __restrict__ packC,
    const unsigned short* __restrict__ HTbf2, const unsigned short* __restrict__ Wbf,
    const float* __restrict__ bias, float* __restrict__ out)
{
    __shared__ unsigned short S2[2][8][256];       // 8 KB (verified R6 path)

    const int t = threadIdx.x;
    const int lane = t & 63, wv = t >> 6;
    const int dir = wv >> 1, rt = wv & 1;
    const int b  = blockIdx.x & 7;            // XCD-pinned batch
    const int v0 = (blockIdx.x >> 3) * 8;
    const int r = lane & 15, kb = lane >> 4;

    const unsigned short* HTg = HTbf2 + (size_t)b * 32768;

    // ---- A-operand bits straight from global packs (L2-hot, 64B/lane) ----
    const int vloc = rt * 4 + (r >> 2);
    const unsigned int rep = (unsigned int)(r & 3) * 0x55555555u;
    const unsigned short* prow = (const unsigned short*)(
        (dir ? packC : packR) + ((size_t)b * NN + v0 + vloc) * 32);
    unsigned int bits0  = prow[kb];        unsigned int bits1  = prow[4 + kb];
    unsigned int bits2  = prow[8 + kb];    unsigned int bits3  = prow[12 + kb];
    unsigned int bits4  = prow[16 + kb];   unsigned int bits5  = prow[20 + kb];
    unsigned int bits6  = prow[24 + kb];   unsigned int bits7  = prow[28 + kb];
    unsigned int bits8  = prow[32 + kb];   unsigned int bits9  = prow[36 + kb];
    unsigned int bits10 = prow[40 + kb];   unsigned int bits11 = prow[44 + kb];
    unsigned int bits12 = prow[48 + kb];   unsigned int bits13 = prow[52 + kb];
    unsigned int bits14 = prow[56 + kb];   unsigned int bits15 = prow[60 + kb];

    // ---- phase 1: S[(v,c),e] = sum_w onehot * h ----
    // B-fragment = 64 lanes x 16B CONSECUTIVE global load (1KB/instr, L2-resident:
    // all 64 blocks of this XCD read the same 64KB slab; exact R9-verified mapping).
    f32x4 acc[4] = {f32x4{0,0,0,0}, f32x4{0,0,0,0}, f32x4{0,0,0,0}, f32x4{0,0,0,0}};
    #pragma unroll
    for (int c = 0; c < 4; ++c) {
        #pragma unroll
        for (int kc = 0; kc < 4; ++kc) {
            unsigned int bits;
            switch (c * 4 + kc) {         // compile-time after unroll
                case 0:  bits = bits0;  break;  case 1:  bits = bits1;  break;
                case 2:  bits = bits2;  break;  case 3:  bits = bits3;  break;
                case 4:  bits = bits4;  break;  case 5:  bits = bits5;  break;
                case 6:  bits = bits6;  break;  case 7:  bits = bits7;  break;
                case 8:  bits = bits8;  break;  case 9:  bits = bits9;  break;
                case 10: bits = bits10; break;  case 11: bits = bits11; break;
                case 12: bits = bits12; break;  case 13: bits = bits13; break;
                case 14: bits = bits14; break;  default: bits = bits15; break;
            }
            bf16x8 afrag = onehot_packed(bits, rep);
            #pragma unroll
            for (int n = 0; n < 4; ++n) {
                int s = (c * 4 + kc) * 4 + n;
                bf16x8 bfrag = *(const bf16x8*)&HTg[(size_t)s * 512 + lane * 8];
                acc[n] = __builtin_amdgcn_mfma_f32_16x16x32_bf16(afrag, bfrag, acc[n], 0, 0, 0);
            }
        }
    }

    // ---- S -> LDS (bf16, XOR-swizzled rows; verified R6 path) ----
    #pragma unroll
    for (int ct = 0; ct < 4; ++ct) {
        #pragma unroll
        for (int rg = 0; rg < 4; ++rg) {
            int row_g = rt * 16 + kb * 4 + rg;        // 0..31 = (v,c)
            int vv = row_g >> 2, cc2 = row_g & 3;
            int e = ct * 16 + r;
            int rb = (cc2 * 128 + e * 2) ^ ((vv & 7) << 4);
            *(unsigned short*)((char*)&S2[dir][vv][0] + rb) = f2bf(acc[ct][rg]);
        }
    }
    __syncthreads();   // the ONLY barrier in the kernel

    // ---- phase 2: out[v, dir*64+d] = sum_{c,e} S[v,(c,e)] * W[(c,e),d] + bias ----
    f32x4 acc2[2] = {f32x4{0,0,0,0}, f32x4{0,0,0,0}};
    #pragma unroll
    for (int kc = 0; kc < 8; ++kc) {
        int vv = r & 7;                               // A rows 8..15 duplicate 0..7
        int kbase = kc * 32 + kb * 8;
        int rb = (kbase * 2) ^ (vv << 4);
        bf16x8 a2 = *(const bf16x8*)((const char*)&S2[dir][vv][0] + rb);
        #pragma unroll
        for (int j = 0; j < 2; ++j) {
            int d = (rt * 2 + j) * 16 + r;
            bf16x8 b2 = *(const bf16x8*)&Wbf[(dir * DD + d) * 256 + kbase];
            acc2[j] = __builtin_amdgcn_mfma_f32_16x16x32_bf16(a2, b2, acc2[j], 0, 0, 0);
        }
    }
    #pragma unroll
    for (int j = 0; j < 2; ++j) {
        int d = (rt * 2 + j) * 16 + r;
        float bs = bias[dir * DD + d];
        #pragma unroll
        for (int rg = 0; rg < 4; ++rg) {
            int row = kb * 4 + rg;                    // duplicated rows >=8 skipped
            if (row < 8)
                out[((size_t)(b * NN + v0 + row)) * (2 * DD) + dir * DD + d] = acc2[j][rg] + bs;
        }
    }
}

// ---------------- fallback (R1 kernel, used only if ws too small) ----------------
__global__ __launch_bounds__(256) void msg_kernel(
    const float* __restrict__ h, const int* __restrict__ adj,
    const float* __restrict__ Min, const float* __restrict__ Mout,
    const float* __restrict__ bias, float* __restrict__ out)
{
    __shared__ __align__(16) float S[4][2][4][DD];
    const int lane = threadIdx.x & 63, wslot = threadIdx.x >> 6;
    const int wid = blockIdx.x * 4 + wslot;
    const int b = wid >> 9, v = wid & (NN - 1);
    const float* hb = h + (size_t)b * NN * DD;
    const int* adjb = adj + (size_t)b * NN * NN;
    float tot = 0.f, ain1 = 0.f, ain2 = 0.f, ain3 = 0.f, aout1 = 0.f, aout2 = 0.f, aout3 = 0.f;
    for (int w0 = 0; w0 < NN; w0 += 64) {
        int cin_chunk = adjb[v * NN + (w0 + lane)];
        int cout_chunk = adjb[(w0 + lane) * NN + v];
        #pragma unroll
        for (int k = 0; k < 64; ++k) {
            float hw = hb[(w0 + k) * DD + lane];
            int cin = __builtin_amdgcn_readlane(cin_chunk, k);
            int cout = __builtin_amdgcn_readlane(cout_chunk, k);
            tot += hw;
            ain1 = fmaf((cin == 1) ? 1.f : 0.f, hw, ain1);
            ain2 = fmaf((cin == 2) ? 1.f : 0.f, hw, ain2);
            ain3 = fmaf((cin == 3) ? 1.f : 0.f, hw, ain3);
            aout1 = fmaf((cout == 1) ? 1.f : 0.f, hw, aout1);
            aout2 = fmaf((cout == 2) ? 1.f : 0.f, hw, aout2);
            aout3 = fmaf((cout == 3) ? 1.f : 0.f, hw, aout3);
        }
    }
    S[wslot][0][0][lane] = tot - ain1 - ain2 - ain3;
    S[wslot][0][1][lane] = ain1; S[wslot][0][2][lane] = ain2; S[wslot][0][3][lane] = ain3;
    S[wslot][1][0][lane] = tot - aout1 - aout2 - aout3;
    S[wslot][1][1][lane] = aout1; S[wslot][1][2][lane] = aout2; S[wslot][1][3][lane] = aout3;
    __syncthreads();
    float o_in = 0.f, o_out = 0.f;
    #pragma unroll
    for (int c = 0; c < 4; ++c)
        for (int e0 = 0; e0 < DD; e0 += 4) {
            float4 mi = *reinterpret_cast<const float4*>(&Min[(c * DD + lane) * DD + e0]);
            float4 mo = *reinterpret_cast<const float4*>(&Mout[(c * DD + lane) * DD + e0]);
            float4 si = *reinterpret_cast<const float4*>(&S[wslot][0][c][e0]);
            float4 so = *reinterpret_cast<const float4*>(&S[wslot][1][c][e0]);
            o_in = fmaf(mi.x, si.x, fmaf(mi.y, si.y, fmaf(mi.z, si.z, fmaf(mi.w, si.w, o_in))));
            o_out = fmaf(mo.x, so.x, fmaf(mo.y, so.y, fmaf(mo.z, so.z, fmaf(mo.w, so.w, o_out))));
        }
    float* ov = out + (size_t)(b * NN + v) * (2 * DD);
    ov[lane] = o_in + bias[lane];
    ov[DD + lane] = o_out + bias[DD + lane];
}

extern "C" void kernel_launch(void* const* d_in, const int* in_sizes, int n_in,
                              void* d_out, int out_size, void* d_ws, size_t ws_size,
                              hipStream_t stream) {
    const float* node_state = (const float*)d_in[0];
    const int*   adj_mat    = (const int*)  d_in[1];
    const float* matrix_in  = (const float*)d_in[2];
    const float* matrix_out = (const float*)d_in[3];
    const float* bias       = (const float*)d_in[4];
    float* out = (float*)d_out;

    const size_t PACKR_OFF = 0;                                  // 512 KB
    const size_t PACKC_OFF = (size_t)NB * NN * 32 * 4;           // +512 KB
    const size_t HT_OFF    = PACKC_OFF + (size_t)NB * NN * 32 * 4;
    const size_t W_OFF     = HT_OFF + (size_t)NB * 32768 * 2;    // +512 KB
    const size_t NEED      = W_OFF + (size_t)2 * DD * 256 * 2;   // +64 KB

    if (ws_size < NEED) {   // scratch too small: proven-correct R1 path
        msg_kernel<<<NB * NN / 4, 256, 0, stream>>>(node_state, adj_mat, matrix_in,
                                                    matrix_out, bias, out);
        return;
    }
    unsigned int*   packR = (unsigned int*)((char*)d_ws + PACKR_OFF);
    unsigned int*   packC = (unsigned int*)((char*)d_ws + PACKC_OFF);
    unsigned short* HTbf2 = (unsigned short*)((char*)d_ws + HT_OFF);
    unsigned short* Wbf   = (unsigned short*)((char*)d_ws + W_OFF);

    prep_kernel<<<704, 256, 0, stream>>>(node_state, adj_mat, matrix_in, matrix_out,
                                         packR, packC, HTbf2, Wbf);
    msg_mfma_kernel<<<NB * NN / 8, 256, 0, stream>>>(packR, packC, HTbf2, Wbf, bias, out);
}

// Round 13
// 20.131 us; speedup vs baseline: 1.1282x; 1.0596x over previous
//
#include <hip/hip_runtime.h>

#define NB 8
#define NN 512
#define DD 64

typedef short bf16x8 __attribute__((ext_vector_type(8)));
typedef float f32x4 __attribute__((ext_vector_type(4)));

__device__ __forceinline__ unsigned short f2bf(float f) {
    unsigned int x = __builtin_bit_cast(unsigned int, f);
    x += 0x7FFFu + ((x >> 16) & 1u);      // round-to-nearest-even (finite inputs)
    return (unsigned short)(x >> 16);
}

__device__ __forceinline__ void gload_lds16(const void* g, void* lds) {
    __builtin_amdgcn_global_load_lds(
        (const __attribute__((address_space(1))) unsigned int*)g,
        (__attribute__((address_space(3))) unsigned int*)lds, 16, 0, 0);
}

// one-hot A-fragment from 16 packed 2-bit fields; rep = cls * 0x55555555
__device__ __forceinline__ bf16x8 onehot_packed(unsigned int bits, unsigned int rep) {
    unsigned int x = bits ^ rep;           // field == 0 where class matches
    unsigned int y = x | (x >> 1);
    unsigned int m = ~y & 0x55555555u;     // bit 2i = match_i
    union { unsigned int u[4]; bf16x8 v; } r;
    #pragma unroll
    for (int j = 0; j < 4; ++j) {
        unsigned int f = m >> (4 * j);
        r.u[j] = ((f & 1u) ? 0x3F80u : 0u) | ((f & 4u) ? 0x3F800000u : 0u);
    }
    return r.v;
}

// ---- prep: adj read ONCE -> packR+packC; h -> HTbf2 (SLAB layout); M -> Wbf ----
// HTbf2 slab layout (u16): [b][slab=(c*4+kc)*4+n][kb][r][j]
//   = bf16(h[b][ w = c*128+kc*32+kb*8+j ][ e = n*16+r ])
// flat u16 idx = b*32768 + slab*512 + kb*128 + r*8 + j
// => one MFMA fragment set (c,kc,n) is 64 lanes x 16B CONSECUTIVE in LDS.
__global__ __launch_bounds__(256) void prep_kernel(
    const float* __restrict__ h, const int* __restrict__ adj,
    const float* __restrict__ Min, const float* __restrict__ Mout,
    unsigned int* __restrict__ packR, unsigned int* __restrict__ packC,
    unsigned short* __restrict__ HTbf2, unsigned short* __restrict__ Wbf)
{
    const int blk = blockIdx.x, t = threadIdx.x;
    if (blk < 512) {                       // adj tile: emit row-pack AND col-pack
        __shared__ int tile[64][65];
        const int b = blk >> 6, ti = blk & 63;
        const int tr = (ti >> 3) * 64, tc = (ti & 7) * 64;
        const int* src = adj + (size_t)b * NN * NN;
        #pragma unroll
        for (int i = 0; i < 16; ++i) {
            int idx = i * 256 + t, rr = idx >> 6, cc = idx & 63;
            tile[rr][cc] = src[(size_t)(tr + rr) * NN + tc + cc];
        }
        __syncthreads();
        {
            int r = t >> 2, g = t & 3;
            unsigned int ur = 0, uc = 0;
            #pragma unroll
            for (int j = 0; j < 16; ++j) {
                ur |= ((unsigned int)tile[r][16 * g + j] & 3u) << (2 * j);
                uc |= ((unsigned int)tile[16 * g + j][r] & 3u) << (2 * j);
            }
            packR[((size_t)b * NN + tr + r) * 32 + (tc >> 4) + g] = ur;
            packC[((size_t)b * NN + tc + r) * 32 + (tr >> 4) + g] = uc;
        }
    } else if (blk < 576) {                // h -> HTbf2 slab image, tiled
        __shared__ float tf[64][65];
        const int bb = blk - 512, b = bb >> 3, w0 = (bb & 7) * 64;
        #pragma unroll
        for (int i = 0; i < 16; ++i) {
            int idx = i * 256 + t, w = idx >> 6, e = idx & 63;
            tf[w][e] = h[((size_t)b * NN + w0 + w) * DD + e];   // coalesced
        }
        __syncthreads();
        unsigned int* HT32 = (unsigned int*)HTbf2;
        const int n = t >> 6, r = (t >> 2) & 15, p = t & 3;
        #pragma unroll
        for (int i = 0; i < 8; ++i) {
            int woct = (w0 >> 3) + i;                  // global oct in [0,64)
            int kb = woct & 3, kc = (woct >> 2) & 3, cch = woct >> 4;
            int slab = (cch * 4 + kc) * 4 + n;
            unsigned int lo = f2bf(tf[8 * i + 2 * p][n * 16 + r]);
            unsigned int hi = f2bf(tf[8 * i + 2 * p + 1][n * 16 + r]);
            HT32[(size_t)b * 16384 + slab * 256 + kb * 64 + r * 4 + p] =
                lo | (hi << 16);
        }
    } else {                               // Wbf[dir][d][c*64+e] = bf16(M[c][d][e])
        int idx = (blk - 576) * 256 + t;
        int dir = idx >> 14, d = (idx >> 8) & 63, k = idx & 255;
        int c = k >> 6, e = k & 63;
        const float* M = dir ? Mout : Min;
        Wbf[idx] = f2bf(M[(c * DD + d) * DD + e]);
    }
}

// ---------------- main: one-hot MFMA, slab LDS, full-prefetch single-barrier ----
// block: (b, 8 v's). 4 waves = (dir, rt). ALL of K=512 staged once (64 KB).
__global__ __launch_bounds__(256) void msg_mfma_kernel(
    const unsigned int* __restrict__ packR, const unsigned int* __restrict__ packC,
    const unsigned short* __restrict__ HTbf2, const unsigned short* __restrict__ Wbf,
    const float* __restrict__ bias, float* __restrict__ out)
{
    __shared__ unsigned short HTX[64][512];        // 64 slabs x 1 KB = 64 KB
    __shared__ unsigned short S2[2][8][256];       // 8 KB, swizzled rows (R6 path)

    const int t = threadIdx.x;
    const int lane = t & 63, wv = t >> 6;
    const int dir = wv >> 1, rt = wv & 1;
    const int b = blockIdx.x >> 6;
    const int v0 = (blockIdx.x & 63) * 8;
    const int r = lane & 15, kb = lane >> 4;

    const unsigned short* HTg = HTbf2 + (size_t)b * 32768;

    // ---- stage all 64 slabs (16/wave), linear src AND dest: no swizzle at all ----
    #pragma unroll
    for (int q = 0; q < 16; ++q) {
        int s = wv * 16 + q;
        gload_lds16(HTg + (size_t)s * 512 + lane * 8, &HTX[s][0]);
    }

    // A-operand bits overlap the staging latency: lane covers (vloc, cls)
    const int vloc = rt * 4 + (r >> 2);
    const unsigned int rep = (unsigned int)(r & 3) * 0x55555555u;
    const unsigned short* prow = (const unsigned short*)(
        (dir ? packC : packR) + ((size_t)b * NN + v0 + vloc) * 32);
    unsigned int bits0  = prow[kb];        unsigned int bits1  = prow[4 + kb];
    unsigned int bits2  = prow[8 + kb];    unsigned int bits3  = prow[12 + kb];
    unsigned int bits4  = prow[16 + kb];   unsigned int bits5  = prow[20 + kb];
    unsigned int bits6  = prow[24 + kb];   unsigned int bits7  = prow[28 + kb];
    unsigned int bits8  = prow[32 + kb];   unsigned int bits9  = prow[36 + kb];
    unsigned int bits10 = prow[40 + kb];   unsigned int bits11 = prow[44 + kb];
    unsigned int bits12 = prow[48 + kb];   unsigned int bits13 = prow[52 + kb];
    unsigned int bits14 = prow[56 + kb];   unsigned int bits15 = prow[60 + kb];

    __syncthreads();   // ONE barrier: drains all 64 slab loads

    // ---- phase 1: S[(v,c),e] = sum_w onehot * h — conflict-free slab reads ----
    f32x4 acc[4] = {f32x4{0,0,0,0}, f32x4{0,0,0,0}, f32x4{0,0,0,0}, f32x4{0,0,0,0}};
    #pragma unroll
    for (int c = 0; c < 4; ++c) {
        #pragma unroll
        for (int kc = 0; kc < 4; ++kc) {
            unsigned int bits;
            switch (c * 4 + kc) {         // compile-time after unroll
                case 0:  bits = bits0;  break;  case 1:  bits = bits1;  break;
                case 2:  bits = bits2;  break;  case 3:  bits = bits3;  break;
                case 4:  bits = bits4;  break;  case 5:  bits = bits5;  break;
                case 6:  bits = bits6;  break;  case 7:  bits = bits7;  break;
                case 8:  bits = bits8;  break;  case 9:  bits = bits9;  break;
                case 10: bits = bits10; break;  case 11: bits = bits11; break;
                case 12: bits = bits12; break;  case 13: bits = bits13; break;
                case 14: bits = bits14; break;  default: bits = bits15; break;
            }
            bf16x8 afrag = onehot_packed(bits, rep);
            #pragma unroll
            for (int n = 0; n < 4; ++n) {
                // slab (c,kc,n): lane ℓ reads bytes [ℓ*16, ℓ*16+16) — linear
                bf16x8 bfrag = *(const bf16x8*)&HTX[(c * 4 + kc) * 4 + n][lane * 8];
                acc[n] = __builtin_amdgcn_mfma_f32_16x16x32_bf16(afrag, bfrag, acc[n], 0, 0, 0);
            }
        }
    }

    // ---- S -> LDS (bf16, XOR-swizzled rows; verified R6 path) ----
    #pragma unroll
    for (int ct = 0; ct < 4; ++ct) {
        #pragma unroll
        for (int rg = 0; rg < 4; ++rg) {
            int row_g = rt * 16 + kb * 4 + rg;        // 0..31 = (v,c)
            int vv = row_g >> 2, cc2 = row_g & 3;
            int e = ct * 16 + r;
            int rb = (cc2 * 128 + e * 2) ^ ((vv & 7) << 4);
            *(unsigned short*)((char*)&S2[dir][vv][0] + rb) = f2bf(acc[ct][rg]);
        }
    }
    __syncthreads();

    // ---- phase 2: out[v, dir*64+d] = sum_{c,e} S[v,(c,e)] * W[(c,e),d] + bias ----
    f32x4 acc2[2] = {f32x4{0,0,0,0}, f32x4{0,0,0,0}};
    #pragma unroll
    for (int kc = 0; kc < 8; ++kc) {
        int vv = r & 7;                               // A rows 8..15 duplicate 0..7
        int kbase = kc * 32 + kb * 8;
        int rb = (kbase * 2) ^ (vv << 4);
        bf16x8 a2 = *(const bf16x8*)((const char*)&S2[dir][vv][0] + rb);
        #pragma unroll
        for (int j = 0; j < 2; ++j) {
            int d = (rt * 2 + j) * 16 + r;
            bf16x8 b2 = *(const bf16x8*)&Wbf[(dir * DD + d) * 256 + kbase];
            acc2[j] = __builtin_amdgcn_mfma_f32_16x16x32_bf16(a2, b2, acc2[j], 0, 0, 0);
        }
    }
    #pragma unroll
    for (int j = 0; j < 2; ++j) {
        int d = (rt * 2 + j) * 16 + r;
        float bs = bias[dir * DD + d];
        #pragma unroll
        for (int rg = 0; rg < 4; ++rg) {
            int row = kb * 4 + rg;                    // duplicated rows >=8 skipped
            if (row < 8)
                out[((size_t)(b * NN + v0 + row)) * (2 * DD) + dir * DD + d] = acc2[j][rg] + bs;
        }
    }
}

// ---------------- fallback (R1 kernel, used only if ws too small) ----------------
__global__ __launch_bounds__(256) void msg_kernel(
    const float* __restrict__ h, const int* __restrict__ adj,
    const float* __restrict__ Min, const float* __restrict__ Mout,
    const float* __restrict__ bias, float* __restrict__ out)
{
    __shared__ __align__(16) float S[4][2][4][DD];
    const int lane = threadIdx.x & 63, wslot = threadIdx.x >> 6;
    const int wid = blockIdx.x * 4 + wslot;
    const int b = wid >> 9, v = wid & (NN - 1);
    const float* hb = h + (size_t)b * NN * DD;
    const int* adjb = adj + (size_t)b * NN * NN;
    float tot = 0.f, ain1 = 0.f, ain2 = 0.f, ain3 = 0.f, aout1 = 0.f, aout2 = 0.f, aout3 = 0.f;
    for (int w0 = 0; w0 < NN; w0 += 64) {
        int cin_chunk = adjb[v * NN + (w0 + lane)];
        int cout_chunk = adjb[(w0 + lane) * NN + v];
        #pragma unroll
        for (int k = 0; k < 64; ++k) {
            float hw = hb[(w0 + k) * DD + lane];
            int cin = __builtin_amdgcn_readlane(cin_chunk, k);
            int cout = __builtin_amdgcn_readlane(cout_chunk, k);
            tot += hw;
            ain1 = fmaf((cin == 1) ? 1.f : 0.f, hw, ain1);
            ain2 = fmaf((cin == 2) ? 1.f : 0.f, hw, ain2);
            ain3 = fmaf((cin == 3) ? 1.f : 0.f, hw, ain3);
            aout1 = fmaf((cout == 1) ? 1.f : 0.f, hw, aout1);
            aout2 = fmaf((cout == 2) ? 1.f : 0.f, hw, aout2);
            aout3 = fmaf((cout == 3) ? 1.f : 0.f, hw, aout3);
        }
    }
    S[wslot][0][0][lane] = tot - ain1 - ain2 - ain3;
    S[wslot][0][1][lane] = ain1; S[wslot][0][2][lane] = ain2; S[wslot][0][3][lane] = ain3;
    S[wslot][1][0][lane] = tot - aout1 - aout2 - aout3;
    S[wslot][1][1][lane] = aout1; S[wslot][1][2][lane] = aout2; S[wslot][1][3][lane] = aout3;
    __syncthreads();
    float o_in = 0.f, o_out = 0.f;
    #pragma unroll
    for (int c = 0; c < 4; ++c)
        for (int e0 = 0; e0 < DD; e0 += 4) {
            float4 mi = *reinterpret_cast<const float4*>(&Min[(c * DD + lane) * DD + e0]);
            float4 mo = *reinterpret_cast<const float4*>(&Mout[(c * DD + lane) * DD + e0]);
            float4 si = *reinterpret_cast<const float4*>(&S[wslot][0][c][e0]);
            float4 so = *reinterpret_cast<const float4*>(&S[wslot][1][c][e0]);
            o_in = fmaf(mi.x, si.x, fmaf(mi.y, si.y, fmaf(mi.z, si.z, fmaf(mi.w, si.w, o_in))));
            o_out = fmaf(mo.x, so.x, fmaf(mo.y, so.y, fmaf(mo.z, so.z, fmaf(mo.w, so.w, o_out))));
        }
    float* ov = out + (size_t)(b * NN + v) * (2 * DD);
    ov[lane] = o_in + bias[lane];
    ov[DD + lane] = o_out + bias[DD + lane];
}

extern "C" void kernel_launch(void* const* d_in, const int* in_sizes, int n_in,
                              void* d_out, int out_size, void* d_ws, size_t ws_size,
                              hipStream_t stream) {
    const float* node_state = (const float*)d_in[0];
    const int*   adj_mat    = (const int*)  d_in[1];
    const float* matrix_in  = (const float*)d_in[2];
    const float* matrix_out = (const float*)d_in[3];
    const float* bias       = (const float*)d_in[4];
    float* out = (float*)d_out;

    const size_t PACKR_OFF = 0;                                  // 512 KB
    const size_t PACKC_OFF = (size_t)NB * NN * 32 * 4;           // +512 KB
    const size_t HT_OFF    = PACKC_OFF + (size_t)NB * NN * 32 * 4;
    const size_t W_OFF     = HT_OFF + (size_t)NB * DD * NN * 2;  // +512 KB
    const size_t NEED      = W_OFF + (size_t)2 * DD * 256 * 2;   // +64 KB

    if (ws_size < NEED) {   // scratch too small: proven-correct R1 path
        msg_kernel<<<NB * NN / 4, 256, 0, stream>>>(node_state, adj_mat, matrix_in,
                                                    matrix_out, bias, out);
        return;
    }
    unsigned int*   packR = (unsigned int*)((char*)d_ws + PACKR_OFF);
    unsigned int*   packC = (unsigned int*)((char*)d_ws + PACKC_OFF);
    unsigned short* HTbf2 = (unsigned short*)((char*)d_ws + HT_OFF);
    unsigned short* Wbf   = (unsigned short*)((char*)d_ws + W_OFF);

    prep_kernel<<<704, 256, 0, stream>>>(node_state, adj_mat, matrix_in, matrix_out,
                                         packR, packC, HTbf2, Wbf);
    msg_mfma_kernel<<<NB * NN / 8, 256, 0, stream>>>(packR, packC, HTbf2, Wbf, bias, out);
}